// Round 1
// baseline (541.043 us; speedup 1.0000x reference)
//
#include <hip/hip_runtime.h>

// Group Query Attention (B=2,S=2048,E=2048,H=32,G=8,D=64) with softmax over
// the HEAD axis (faithful to reference F.softmax(dim=1)).
// Pipeline: cvt->bf16, Q/K/V proj GEMMs (bf16 MFMA), fused all-head attention
// (head-softmax is local per (q,k) -> no online softmax state), out proj GEMM.
// Known issue #1 (round 0): V-transpose staging uses scalar ds_writes with a
// 2-bit swizzle (~16-way bank conflict) -- candidate for tr16-read later.

typedef unsigned short u16;
typedef unsigned int u32;
typedef __attribute__((ext_vector_type(8))) __bf16 bf16x8;
typedef __attribute__((ext_vector_type(4))) float f32x4;
typedef __attribute__((ext_vector_type(4))) float float4_t;

#define GLD16(ldsp, gp)                                                  \
  __builtin_amdgcn_global_load_lds(                                      \
      (__attribute__((address_space(1))) void*)(void*)(gp),              \
      (__attribute__((address_space(3))) void*)(void*)(ldsp), 16, 0, 0)

static __device__ __forceinline__ u16 f2bf(float f) {
  union { float f; u32 u; } v; v.f = f;
  u32 u = v.u;
  u32 r = (u + 0x7fffu + ((u >> 16) & 1u)) >> 16;  // RNE
  return (u16)r;
}

static __device__ __forceinline__ bf16x8 ld8(const u16* p) {
  return *(const bf16x8*)p;
}

// ---------------- fp32 -> bf16 ----------------
__global__ void cvt_bf16(const float* __restrict__ in, u16* __restrict__ out, int n8) {
  int i = blockIdx.x * blockDim.x + threadIdx.x;
  int stride = gridDim.x * blockDim.x;
  for (; i < n8; i += stride) {
    const float4_t* p = (const float4_t*)in + (size_t)i * 2;
    float4_t a = p[0], b = p[1];
    u32 w0 = (u32)f2bf(a[0]) | ((u32)f2bf(a[1]) << 16);
    u32 w1 = (u32)f2bf(a[2]) | ((u32)f2bf(a[3]) << 16);
    u32 w2 = (u32)f2bf(b[0]) | ((u32)f2bf(b[1]) << 16);
    u32 w3 = (u32)f2bf(b[2]) | ((u32)f2bf(b[3]) << 16);
    *(uint4*)(out + (size_t)i * 8) = make_uint4(w0, w1, w2, w3);
  }
}

// ---------------- GEMM: C[M,N] = A[M,K] @ W[N,K]^T + bias ----------------
// 128x128 tile, BK=32, 4 waves each 64x64 (4x4 of 16x16 MFMA).
// LDS staged via global_load_lds(16B); k-chunk XOR swizzle applied by
// pre-swizzling the GLOBAL source (LDS dest must stay linear).
template <bool OUT_BF16>
__global__ __launch_bounds__(256, 2)
void gemm_bt(const u16* __restrict__ A, const u16* __restrict__ Bw,
             const float* __restrict__ bias,
             u16* __restrict__ Cb, float* __restrict__ Cf, int N) {
  constexpr int K = 2048;
  __shared__ u16 As[128 * 32];
  __shared__ u16 Bs[128 * 32];
  const int tid = threadIdx.x;
  const int lane = tid & 63;
  const int w = tid >> 6;
  const int m0 = blockIdx.y * 128;
  const int n0 = blockIdx.x * 128;
  const int wr = (w >> 1) * 64, wc = (w & 1) * 64;
  const int r15 = lane & 15, kq = lane >> 4;

  f32x4 acc[4][4] = {};

  for (int k0 = 0; k0 < K; k0 += 32) {
#pragma unroll
    for (int i = 0; i < 2; ++i) {
      int c = i * 256 + tid;            // 16B chunk id, 0..511
      int r = c >> 2, ch = c & 3;       // row in tile, chunk within row
      int sc = (ch ^ (r & 3)) * 8;      // swizzled k-offset (elements)
      GLD16(&As[c * 8], &A[(size_t)(m0 + r) * K + k0 + sc]);
      GLD16(&Bs[c * 8], &Bw[(size_t)(n0 + r) * K + k0 + sc]);
    }
    __syncthreads();
    bf16x8 af[4], bfr[4];
#pragma unroll
    for (int mt = 0; mt < 4; ++mt) {
      int r = wr + mt * 16 + r15;
      af[mt] = ld8(&As[r * 32 + ((kq ^ (r15 & 3)) * 8)]);
    }
#pragma unroll
    for (int nt = 0; nt < 4; ++nt) {
      int r = wc + nt * 16 + r15;
      bfr[nt] = ld8(&Bs[r * 32 + ((kq ^ (r15 & 3)) * 8)]);
    }
#pragma unroll
    for (int mt = 0; mt < 4; ++mt)
#pragma unroll
      for (int nt = 0; nt < 4; ++nt)
        acc[mt][nt] = __builtin_amdgcn_mfma_f32_16x16x32_bf16(af[mt], bfr[nt], acc[mt][nt], 0, 0, 0);
    __syncthreads();
  }
  const int rb = kq * 4;
#pragma unroll
  for (int mt = 0; mt < 4; ++mt) {
#pragma unroll
    for (int nt = 0; nt < 4; ++nt) {
      int col = n0 + wc + nt * 16 + r15;
      float bv = bias[col];
#pragma unroll
      for (int r = 0; r < 4; ++r) {
        int row = m0 + wr + mt * 16 + rb + r;
        float v = acc[mt][nt][r] + bv;
        if constexpr (OUT_BF16) Cb[(size_t)row * N + col] = f2bf(v);
        else                    Cf[(size_t)row * N + col] = v;
      }
    }
  }
}

// ---------------- fused attention ----------------
// Block = (b, 16-row q-tile). 8 waves; wave w owns heads 4w..4w+3.
// Loop k-tiles of 32: stage K (gload_lds, swizzled src) + V (transposed,
// scalar writes, 2-bit swizzle); QK^T -> Sl; softmax over h (thread ->
// one (q,k) position); P (bf16) into Kl region; PV accumulate.
__global__ __launch_bounds__(512, 2)
void attn_fused(const u16* __restrict__ Q, const u16* __restrict__ Kg,
                const u16* __restrict__ Vg, u16* __restrict__ O) {
  __shared__ u16 Kl[32 * 512];     // K tile; reused as P tile [h][q][k]
  __shared__ u16 Vl[8 * 64 * 32];  // V^T: [g][d][kk], kk-chunk swizzled
  __shared__ float Sl[32 * 16 * 33];  // scores [h][q][k], pad 33

  const int tid = threadIdx.x;
  const int lane = tid & 63, w = tid >> 6;
  const int b = blockIdx.x >> 7;
  const int q0 = (blockIdx.x & 127) << 4;
  const int r15 = lane & 15, kq = lane >> 4;

  // Q fragments, hoisted for the whole block (heads 4w..4w+3, d in 2 halves)
  bf16x8 qf[4][2];
#pragma unroll
  for (int hh = 0; hh < 4; ++hh) {
    int h = w * 4 + hh;
#pragma unroll
    for (int t = 0; t < 2; ++t)
      qf[hh][t] = ld8(&Q[(size_t)(b * 2048 + q0 + r15) * 2048 + h * 64 + t * 32 + kq * 8]);
  }

  f32x4 acc[4][4] = {};  // [head][d-chunk] per-wave O accumulator

  for (int k0 = 0; k0 < 2048; k0 += 32) {
    // ---- stage K: linear LDS dest, swizzle via global source ----
#pragma unroll
    for (int i = 0; i < 4; ++i) {
      int c = i * 512 + tid;          // 0..2047 chunks of 16B
      int kk = c >> 6, ch = c & 63;
      GLD16(&Kl[c * 8], &Kg[(size_t)(b * 2048 + k0 + kk) * 512 + ((ch ^ (kk & 7)) * 8)]);
    }
    // ---- stage V transposed: Vl[g][d][kk ^ ((d>>3)&3)<<3] ----
#pragma unroll
    for (int i = 0; i < 4; ++i) {
      int c = i * 512 + tid;
      int kk = c >> 6, p = c & 63;
      bf16x8 v = ld8(&Vg[(size_t)(b * 2048 + k0 + kk) * 512 + p * 8]);
      int g = p >> 3, d0 = (p & 7) * 8;
      int kks = kk ^ ((p & 3) << 3);  // (d>>3)&3 == p&3 for this thread
#pragma unroll
      for (int j = 0; j < 8; ++j)
        Vl[g * 2048 + (d0 + j) * 32 + kks] = ((const u16*)&v)[j];
    }
    __syncthreads();

    // ---- QK^T -> Sl (scaled) ----
#pragma unroll
    for (int hh = 0; hh < 4; ++hh) {
      int h = w * 4 + hh, g = h & 7;
#pragma unroll
      for (int ko = 0; ko < 2; ++ko) {
        f32x4 s = {};
#pragma unroll
        for (int t = 0; t < 2; ++t) {
          int u = g * 8 + t * 4 + kq;  // 16B chunk within K row
          bf16x8 bk = ld8(&Kl[(ko * 16 + r15) * 512 + ((u ^ (r15 & 7)) * 8)]);
          s = __builtin_amdgcn_mfma_f32_16x16x32_bf16(qf[hh][t], bk, s, 0, 0, 0);
        }
#pragma unroll
        for (int r = 0; r < 4; ++r)
          Sl[(h * 16 + kq * 4 + r) * 33 + ko * 16 + r15] = s[r] * 0.125f;
      }
    }
    __syncthreads();

    // ---- softmax over heads: thread -> (q = tid>>5, k = tid&31) ----
    {
      int q = tid >> 5, kk = tid & 31;
      float sv[32];
      float m = -1e30f;
#pragma unroll
      for (int h = 0; h < 32; ++h) { sv[h] = Sl[(h * 16 + q) * 33 + kk]; m = fmaxf(m, sv[h]); }
      float sum = 0.f;
#pragma unroll
      for (int h = 0; h < 32; ++h) { sv[h] = __expf(sv[h] - m); sum += sv[h]; }
      float rs = 1.0f / sum;
      int kks = kk ^ ((q & 3) << 3);
#pragma unroll
      for (int h = 0; h < 32; ++h)
        Kl[(h * 16 + q) * 32 + kks] = f2bf(sv[h] * rs);  // P (bf16) into Kl region
    }
    __syncthreads();

    // ---- PV accumulate ----
#pragma unroll
    for (int hh = 0; hh < 4; ++hh) {
      int h = w * 4 + hh, g = h & 7;
      bf16x8 pa = ld8(&Kl[(h * 16 + r15) * 32 + ((kq ^ (r15 & 3)) * 8)]);
#pragma unroll
      for (int nt = 0; nt < 4; ++nt) {
        int d = nt * 16 + r15;
        int s2 = (d >> 3) & 3;
        bf16x8 vb = ld8(&Vl[g * 2048 + d * 32 + ((kq ^ s2) * 8)]);
        acc[hh][nt] = __builtin_amdgcn_mfma_f32_16x16x32_bf16(pa, vb, acc[hh][nt], 0, 0, 0);
      }
    }
    __syncthreads();
  }

  // ---- epilogue: O[b, q, h*64 + d] bf16 ----
#pragma unroll
  for (int hh = 0; hh < 4; ++hh) {
    int h = w * 4 + hh;
#pragma unroll
    for (int nt = 0; nt < 4; ++nt) {
#pragma unroll
      for (int r = 0; r < 4; ++r) {
        int row = q0 + kq * 4 + r;
        O[(size_t)(b * 2048 + row) * 2048 + h * 64 + nt * 16 + r15] = f2bf(acc[hh][nt][r]);
      }
    }
  }
}

// ---------------- launcher ----------------
extern "C" void kernel_launch(void* const* d_in, const int* in_sizes, int n_in,
                              void* d_out, int out_size, void* d_ws, size_t ws_size,
                              hipStream_t stream) {
  (void)in_sizes; (void)n_in; (void)out_size; (void)ws_size;
  const float* x    = (const float*)d_in[0];
  const float* wq_w = (const float*)d_in[1];
  const float* wq_b = (const float*)d_in[2];
  const float* wk_w = (const float*)d_in[3];
  const float* wk_b = (const float*)d_in[4];
  const float* wv_w = (const float*)d_in[5];
  const float* wv_b = (const float*)d_in[6];
  const float* wo_w = (const float*)d_in[7];
  const float* wo_b = (const float*)d_in[8];
  float* out = (float*)d_out;

  char* p = (char*)d_ws;
  u16* xb  = (u16*)p; p += (size_t)4096 * 2048 * 2;
  u16* wqb = (u16*)p; p += (size_t)2048 * 2048 * 2;
  u16* wkb = (u16*)p; p += (size_t)512 * 2048 * 2;
  u16* wvb = (u16*)p; p += (size_t)512 * 2048 * 2;
  u16* wob = (u16*)p; p += (size_t)2048 * 2048 * 2;
  u16* Qb  = (u16*)p; p += (size_t)4096 * 2048 * 2;
  u16* Kb  = (u16*)p; p += (size_t)4096 * 512 * 2;
  u16* Vb  = (u16*)p; p += (size_t)4096 * 512 * 2;
  u16* Ob  = (u16*)p; p += (size_t)4096 * 2048 * 2;
  // total ws use ~80 MB

  auto cvt = [&](const float* in, u16* o, int n) {
    int n8 = n / 8;
    int grid = (n8 + 255) / 256; if (grid > 2048) grid = 2048;
    hipLaunchKernelGGL(cvt_bf16, dim3(grid), dim3(256), 0, stream, in, o, n8);
  };
  cvt(x, xb, 4096 * 2048);
  cvt(wq_w, wqb, 2048 * 2048);
  cvt(wk_w, wkb, 512 * 2048);
  cvt(wv_w, wvb, 512 * 2048);
  cvt(wo_w, wob, 2048 * 2048);

  // Q/K/V projections
  hipLaunchKernelGGL((gemm_bt<true>),  dim3(16, 32), dim3(256), 0, stream,
                     xb, wqb, wq_b, Qb, (float*)nullptr, 2048);
  hipLaunchKernelGGL((gemm_bt<true>),  dim3(4, 32),  dim3(256), 0, stream,
                     xb, wkb, wk_b, Kb, (float*)nullptr, 512);
  hipLaunchKernelGGL((gemm_bt<true>),  dim3(4, 32),  dim3(256), 0, stream,
                     xb, wvb, wv_b, Vb, (float*)nullptr, 512);

  // fused all-head attention with head-axis softmax
  hipLaunchKernelGGL(attn_fused, dim3(256), dim3(512), 0, stream, Qb, Kb, Vb, Ob);

  // output projection (fp32 out)
  hipLaunchKernelGGL((gemm_bt<false>), dim3(16, 32), dim3(256), 0, stream,
                     Ob, wob, wo_b, (u16*)nullptr, out, 2048);
}